// Round 2
// baseline (176.191 us; speedup 1.0000x reference)
//
#include <hip/hip_runtime.h>

#define FEAT   256
#define K2     512      // 2*FEAT
#define NNODES 100000
#define BATCH  50000
#define NS     10
#define EMBED  256
#define BN     64
#define NBLK   ((BATCH + BN - 1) / BN)   // 782

typedef __attribute__((ext_vector_type(8))) __bf16         bf16x8;
typedef __attribute__((ext_vector_type(8))) unsigned short ushort8;
typedef __attribute__((ext_vector_type(4))) float          f32x4;

static __device__ __forceinline__ unsigned short f2bf(float x) {
    unsigned int u = __builtin_bit_cast(unsigned int, x);
    u += 0x7FFFu + ((u >> 16) & 1u);
    return (unsigned short)(u >> 16);
}
static __device__ __forceinline__ float bf2f(unsigned short h) {
    return __builtin_bit_cast(float, (unsigned int)h << 16);
}

// ---- features f32 -> bf16 (streaming, 12500 blocks) ----
__global__ void fconv_kernel(const float* __restrict__ f,
                             unsigned short* __restrict__ fb) {
    int i = blockIdx.x * blockDim.x + threadIdx.x;    // one 8-elem chunk each
    const f32x4* src = (const f32x4*)(f + (size_t)i * 8);
    f32x4 a = src[0], b = src[1];
    ushort8 h;
    h[0]=f2bf(a[0]); h[1]=f2bf(a[1]); h[2]=f2bf(a[2]); h[3]=f2bf(a[3]);
    h[4]=f2bf(b[0]); h[5]=f2bf(b[1]); h[6]=f2bf(b[2]); h[7]=f2bf(b[3]);
    ((ushort8*)fb)[i] = h;
}

// ---- weight f32 -> bf16, packed FRAGMENT-MAJOR ----
// layout: [kt(8)][mblk(16)][ks(2)][lane(64)][8 elems]
// element (lane): row = mblk*16 + (lane&15), col = kt*64 + ks*32 + (lane>>4)*8
__global__ void wpack_kernel(const float* __restrict__ w,
                             unsigned short* __restrict__ wp) {
    int c    = blockIdx.x * blockDim.x + threadIdx.x;  // 16384 chunks
    int lane = c & 63;
    int ks   = (c >> 6) & 1;
    int mblk = (c >> 7) & 15;
    int kt   = c >> 11;
    int row  = mblk * 16 + (lane & 15);
    int col  = kt * 64 + ks * 32 + (lane >> 4) * 8;
    const f32x4* src = (const f32x4*)(w + row * K2 + col);
    f32x4 a = src[0], b = src[1];
    ushort8 h;
    h[0]=f2bf(a[0]); h[1]=f2bf(a[1]); h[2]=f2bf(a[2]); h[3]=f2bf(a[3]);
    h[4]=f2bf(b[0]); h[5]=f2bf(b[1]); h[6]=f2bf(b[2]); h[7]=f2bf(b[3]);
    ((ushort8*)wp)[c] = h;
}

// ---- fused: gather-once-per-block into LDS, then barrier-free MFMA ----
// out[m][n] = relu(sum_k W[m][k]*combined[n][k]); LDS swizzle: chunk ^= (row&7) on low 3 bits
template <bool BF16F>
__global__ __launch_bounds__(512, 4) void gemm_fused(
    const float* __restrict__ features,
    const unsigned short* __restrict__ fbf,
    const unsigned short* __restrict__ wp,
    const int* __restrict__ nodes,
    const int* __restrict__ neigh,
    float* __restrict__ out) {

    __shared__ __align__(16) unsigned short lB[BN * K2];   // 64 KB

    const int tid = threadIdx.x;
    const int nb0 = blockIdx.x * BN;

    // ================= gather phase (once per block) =================
    {
        const int r  = tid >> 3;     // 0..63  batch row within tile
        const int g  = tid & 7;      // 0..7   64-col span [g*64, g*64+64)
        const int n  = nb0 + r;
        const int rx = r & 7;
        unsigned short* dst = lB + r * K2 + g * 64;  // chunk i -> dst[(i^rx)*8]

        if (n >= BATCH) {
            ushort8 z = {0,0,0,0,0,0,0,0};
            #pragma unroll
            for (int i = 0; i < 8; ++i) *(ushort8*)&dst[(i ^ rx) * 8] = z;
        } else if (g < 4) {
            // self half: k = g*64 .. +64
            if (BF16F) {
                const int base = nodes[n] * FEAT + g * 64;
                #pragma unroll
                for (int i = 0; i < 8; ++i) {
                    ushort8 v = *(const ushort8*)&fbf[base + i * 8];
                    *(ushort8*)&dst[(i ^ rx) * 8] = v;
                }
            } else {
                const float* src = features + (size_t)nodes[n] * FEAT + g * 64;
                #pragma unroll
                for (int i = 0; i < 8; ++i) {
                    f32x4 a = *(const f32x4*)(src + i * 8);
                    f32x4 b = *(const f32x4*)(src + i * 8 + 4);
                    ushort8 h;
                    h[0]=f2bf(a[0]); h[1]=f2bf(a[1]); h[2]=f2bf(a[2]); h[3]=f2bf(a[3]);
                    h[4]=f2bf(b[0]); h[5]=f2bf(b[1]); h[6]=f2bf(b[2]); h[7]=f2bf(b[3]);
                    *(ushort8*)&dst[(i ^ rx) * 8] = h;
                }
            }
        } else {
            // neighbor-mean half: k-offset into features = (g-4)*64
            const int koff = (g - 4) * 64;
            int base[NS];
            #pragma unroll
            for (int s = 0; s < NS; ++s)
                base[s] = neigh[n * NS + s] * FEAT + koff;

            #pragma unroll
            for (int h2 = 0; h2 < 2; ++h2) {          // two 32-col halves
                float acc[32];
                #pragma unroll
                for (int e = 0; e < 32; ++e) acc[e] = 0.f;
                if (BF16F) {
                    #pragma unroll
                    for (int s = 0; s < NS; ++s) {
                        #pragma unroll
                        for (int q = 0; q < 4; ++q) {
                            ushort8 v = *(const ushort8*)&fbf[base[s] + h2 * 32 + q * 8];
                            #pragma unroll
                            for (int e = 0; e < 8; ++e) acc[q * 8 + e] += bf2f(v[e]);
                        }
                    }
                } else {
                    #pragma unroll
                    for (int s = 0; s < NS; ++s) {
                        const float* src = features + (size_t)base[s] + h2 * 32;
                        #pragma unroll
                        for (int q = 0; q < 8; ++q) {
                            f32x4 v = *(const f32x4*)(src + q * 4);
                            #pragma unroll
                            for (int e = 0; e < 4; ++e) acc[q * 4 + e] += v[e];
                        }
                    }
                }
                #pragma unroll
                for (int q = 0; q < 4; ++q) {
                    ushort8 hh;
                    #pragma unroll
                    for (int e = 0; e < 8; ++e) hh[e] = f2bf(acc[q * 8 + e] * 0.1f);
                    int i = h2 * 4 + q;
                    *(ushort8*)&dst[(i ^ rx) * 8] = hh;
                }
            }
        }
    }
    __syncthreads();

    // ================= MFMA phase (no further barriers) =================
    const int w    = tid >> 6;       // 8 waves: wm = w>>1 (64 m-rows), wn = w&1 (32 n-cols)
    const int lane = tid & 63;
    const int lr   = lane & 15;
    const int lg   = lane >> 4;
    const int wm   = w >> 1;
    const int wn   = w & 1;

    f32x4 acc[4][2] = {};

    #pragma unroll
    for (int kt = 0; kt < 8; ++kt) {
        bf16x8 af[4][2], bfr[2][2];
        #pragma unroll
        for (int i = 0; i < 4; ++i)
            #pragma unroll
            for (int ks = 0; ks < 2; ++ks)
                af[i][ks] = *(const bf16x8*)(wp +
                    ((((kt * 16 + wm * 4 + i) * 2 + ks) * 64 + lane) << 3));
        #pragma unroll
        for (int j = 0; j < 2; ++j)
            #pragma unroll
            for (int ks = 0; ks < 2; ++ks) {
                int rb = wn * 32 + j * 16 + lr;
                int ch = kt * 8 + ((ks * 4 + lg) ^ (rb & 7));
                bfr[j][ks] = *(const bf16x8*)&lB[rb * K2 + ch * 8];
            }
        #pragma unroll
        for (int ks = 0; ks < 2; ++ks)
            #pragma unroll
            for (int i = 0; i < 4; ++i)
                #pragma unroll
                for (int j = 0; j < 2; ++j)
                    acc[i][j] = __builtin_amdgcn_mfma_f32_16x16x32_bf16(
                        af[i][ks], bfr[j][ks], acc[i][j], 0, 0, 0);
    }

    // epilogue: relu + store. C/D: col=lane&15, row=(lane>>4)*4+reg
    #pragma unroll
    for (int i = 0; i < 4; ++i) {
        int m0 = wm * 64 + i * 16 + lg * 4;
        #pragma unroll
        for (int j = 0; j < 2; ++j) {
            int n = nb0 + wn * 32 + j * 16 + lr;
            if (n < BATCH) {
                #pragma unroll
                for (int rg = 0; rg < 4; ++rg) {
                    float v = acc[i][j][rg];
                    out[(size_t)(m0 + rg) * BATCH + n] = v > 0.f ? v : 0.f;
                }
            }
        }
    }
}

extern "C" void kernel_launch(void* const* d_in, const int* in_sizes, int n_in,
                              void* d_out, int out_size, void* d_ws, size_t ws_size,
                              hipStream_t stream) {
    const float* features = (const float*)d_in[0];
    const float* weight   = (const float*)d_in[1];
    const int*   nodes    = (const int*)d_in[2];
    const int*   neigh    = (const int*)d_in[3];
    float* out = (float*)d_out;

    unsigned short* wp  = (unsigned short*)d_ws;              // 256 KB packed weight
    unsigned short* fbf = wp + (size_t)EMBED * K2;            // 51.2 MB bf16 features

    const size_t need = (size_t)EMBED * K2 * 2 + (size_t)NNODES * FEAT * 2;

    wpack_kernel<<<(EMBED * K2 / 8) / 256, 256, 0, stream>>>(weight, wp);

    if (ws_size >= need) {
        fconv_kernel<<<(NNODES * FEAT / 8) / 256, 256, 0, stream>>>(features, fbf);
        gemm_fused<true><<<NBLK, 512, 0, stream>>>(features, fbf, wp, nodes, neigh, out);
    } else {
        gemm_fused<false><<<NBLK, 512, 0, stream>>>(features, fbf, wp, nodes, neigh, out);
    }
}

// Round 3
// 97.811 us; speedup vs baseline: 1.8013x; 1.8013x over previous
//
#include <hip/hip_runtime.h>

#define FEAT   256
#define K2     512      // 2*FEAT
#define NNODES 100000
#define BATCH  50000
#define NS     10
#define EMBED  256
#define BN     32
#define NBLK   ((BATCH + BN - 1) / BN)   // 1563

typedef __attribute__((ext_vector_type(8))) __bf16         bf16x8;
typedef __attribute__((ext_vector_type(8))) unsigned short ushort8;
typedef __attribute__((ext_vector_type(4))) float          f32x4;

static __device__ __forceinline__ unsigned short f2bf(float x) {
    unsigned int u = __builtin_bit_cast(unsigned int, x);
    u += 0x7FFFu + ((u >> 16) & 1u);
    return (unsigned short)(u >> 16);
}
static __device__ __forceinline__ float bf2f(unsigned short h) {
    return __builtin_bit_cast(float, (unsigned int)h << 16);
}

// ---- features f32 -> bf16 (streaming) ----
__global__ void fconv_kernel(const float* __restrict__ f,
                             unsigned short* __restrict__ fb) {
    int i = blockIdx.x * blockDim.x + threadIdx.x;
    const f32x4* src = (const f32x4*)(f + (size_t)i * 8);
    f32x4 a = src[0], b = src[1];
    ushort8 h;
    h[0]=f2bf(a[0]); h[1]=f2bf(a[1]); h[2]=f2bf(a[2]); h[3]=f2bf(a[3]);
    h[4]=f2bf(b[0]); h[5]=f2bf(b[1]); h[6]=f2bf(b[2]); h[7]=f2bf(b[3]);
    ((ushort8*)fb)[i] = h;
}

// ---- weight f32 -> bf16, fragment-major: [kt(8)][mblk(16)][ks(2)][lane(64)][8] ----
__global__ void wpack_kernel(const float* __restrict__ w,
                             unsigned short* __restrict__ wp) {
    int c    = blockIdx.x * blockDim.x + threadIdx.x;  // 16384 chunks
    int lane = c & 63;
    int ks   = (c >> 6) & 1;
    int mblk = (c >> 7) & 15;
    int kt   = c >> 11;
    int row  = mblk * 16 + (lane & 15);
    int col  = kt * 64 + ks * 32 + (lane >> 4) * 8;
    const f32x4* src = (const f32x4*)(w + row * K2 + col);
    f32x4 a = src[0], b = src[1];
    ushort8 h;
    h[0]=f2bf(a[0]); h[1]=f2bf(a[1]); h[2]=f2bf(a[2]); h[3]=f2bf(a[3]);
    h[4]=f2bf(b[0]); h[5]=f2bf(b[1]); h[6]=f2bf(b[2]); h[7]=f2bf(b[3]);
    ((ushort8*)wp)[c] = h;
}

// ---- fused: full-lane gather into 32KB LDS, one barrier, MFMA, relu ----
// LDS layout: lB[r][512 cols] as 8 groups g of 8 chunks i (8 cols each);
// swizzle: chunk stored at (i ^ (r&7)) within its group.
template <bool BF16F>
__global__ __launch_bounds__(512, 6) void gemm_fused(
    const float* __restrict__ features,
    const unsigned short* __restrict__ fbf,
    const unsigned short* __restrict__ wp,
    const int* __restrict__ nodes,
    const int* __restrict__ neigh,
    float* __restrict__ out) {

    __shared__ __align__(16) unsigned short lB[BN * K2];   // 32 KB

    const int tid = threadIdx.x;
    const int nb0 = blockIdx.x * BN;

    const int r  = tid >> 4;     // 0..31 batch row in tile
    const int h  = tid & 15;     // 0..15 16-col span
    const int rx = r & 7;
    const int n  = nb0 + r;
    const bool valid = n < BATCH;

    // ---- step 1: self half (all lanes) ----
    {
        ushort8 a = {0,0,0,0,0,0,0,0}, b = {0,0,0,0,0,0,0,0};
        if (valid) {
            const int node = nodes[n];
            if (BF16F) {
                const ushort8* s = (const ushort8*)(fbf + node * FEAT + h * 16);
                a = s[0]; b = s[1];
            } else {
                const f32x4* s = (const f32x4*)(features + (size_t)node * FEAT + h * 16);
                f32x4 x0 = s[0], x1 = s[1], x2 = s[2], x3 = s[3];
                a[0]=f2bf(x0[0]); a[1]=f2bf(x0[1]); a[2]=f2bf(x0[2]); a[3]=f2bf(x0[3]);
                a[4]=f2bf(x1[0]); a[5]=f2bf(x1[1]); a[6]=f2bf(x1[2]); a[7]=f2bf(x1[3]);
                b[0]=f2bf(x2[0]); b[1]=f2bf(x2[1]); b[2]=f2bf(x2[2]); b[3]=f2bf(x2[3]);
                b[4]=f2bf(x3[0]); b[5]=f2bf(x3[1]); b[6]=f2bf(x3[2]); b[7]=f2bf(x3[3]);
            }
        }
        const int g = h >> 2, i0 = (h & 3) * 2;
        unsigned short* dst = lB + r * K2 + g * 64;
        *(ushort8*)&dst[((i0    ) ^ rx) * 8] = a;
        *(ushort8*)&dst[((i0 + 1) ^ rx) * 8] = b;
    }

    // ---- step 2: neighbor mean half (all lanes; one (row,span) task each) ----
    {
        int base[NS];
        #pragma unroll
        for (int s = 0; s < NS; ++s) {
            int idx = valid ? neigh[n * NS + s] : 0;
            base[s] = idx * FEAT + h * 16;
        }
        float acc[16];
        #pragma unroll
        for (int e = 0; e < 16; ++e) acc[e] = 0.f;

        if (BF16F) {
            #pragma unroll
            for (int s = 0; s < NS; ++s) {
                const ushort8* p = (const ushort8*)(fbf + base[s]);
                ushort8 a = p[0], b = p[1];
                #pragma unroll
                for (int e = 0; e < 8; ++e) {
                    acc[e]     += bf2f(a[e]);
                    acc[8 + e] += bf2f(b[e]);
                }
            }
        } else {
            #pragma unroll
            for (int s = 0; s < NS; ++s) {
                const f32x4* p = (const f32x4*)(features + (size_t)base[s]);
                f32x4 x0 = p[0], x1 = p[1], x2 = p[2], x3 = p[3];
                #pragma unroll
                for (int e = 0; e < 4; ++e) {
                    acc[e]      += x0[e];
                    acc[4 + e]  += x1[e];
                    acc[8 + e]  += x2[e];
                    acc[12 + e] += x3[e];
                }
            }
        }
        ushort8 a, b;
        #pragma unroll
        for (int e = 0; e < 8; ++e) {
            a[e] = f2bf(valid ? acc[e]     * 0.1f : 0.f);
            b[e] = f2bf(valid ? acc[8 + e] * 0.1f : 0.f);
        }
        const int g = 4 + (h >> 2), i0 = (h & 3) * 2;
        unsigned short* dst = lB + r * K2 + g * 64;
        *(ushort8*)&dst[((i0    ) ^ rx) * 8] = a;
        *(ushort8*)&dst[((i0 + 1) ^ rx) * 8] = b;
    }
    __syncthreads();

    // ---- MFMA phase: 8 waves, wave -> (wm = 64 m-rows quarter, wn = 16 n-cols half) ----
    const int w    = tid >> 6;
    const int lane = tid & 63;
    const int lr   = lane & 15;
    const int lg   = lane >> 4;
    const int wm   = w >> 1;
    const int wn   = w & 1;

    f32x4 acc[4] = {};

    #pragma unroll
    for (int kt = 0; kt < 8; ++kt) {
        bf16x8 af[4][2], bfr[2];
        #pragma unroll
        for (int i = 0; i < 4; ++i)
            #pragma unroll
            for (int ks = 0; ks < 2; ++ks)
                af[i][ks] = *(const bf16x8*)(wp +
                    ((((kt * 16 + wm * 4 + i) * 2 + ks) * 64 + lane) << 3));
        const int rb = wn * 16 + lr;
        #pragma unroll
        for (int ks = 0; ks < 2; ++ks) {
            int ch = kt * 8 + ((ks * 4 + lg) ^ (rb & 7));
            bfr[ks] = *(const bf16x8*)&lB[rb * K2 + ch * 8];
        }
        #pragma unroll
        for (int ks = 0; ks < 2; ++ks)
            #pragma unroll
            for (int i = 0; i < 4; ++i)
                acc[i] = __builtin_amdgcn_mfma_f32_16x16x32_bf16(
                    af[i][ks], bfr[ks], acc[i], 0, 0, 0);
    }

    // ---- epilogue: relu + nontemporal store. C/D: col=lane&15, row=(lane>>4)*4+reg ----
    const int n2 = nb0 + wn * 16 + lr;
    if (n2 < BATCH) {
        #pragma unroll
        for (int i = 0; i < 4; ++i) {
            int m0 = wm * 64 + i * 16 + lg * 4;
            #pragma unroll
            for (int rg = 0; rg < 4; ++rg) {
                float v = acc[i][rg];
                v = v > 0.f ? v : 0.f;
                __builtin_nontemporal_store(v, &out[(size_t)(m0 + rg) * BATCH + n2]);
            }
        }
    }
}

extern "C" void kernel_launch(void* const* d_in, const int* in_sizes, int n_in,
                              void* d_out, int out_size, void* d_ws, size_t ws_size,
                              hipStream_t stream) {
    const float* features = (const float*)d_in[0];
    const float* weight   = (const float*)d_in[1];
    const int*   nodes    = (const int*)d_in[2];
    const int*   neigh    = (const int*)d_in[3];
    float* out = (float*)d_out;

    unsigned short* wp  = (unsigned short*)d_ws;              // 256 KB packed weight
    unsigned short* fbf = wp + (size_t)EMBED * K2;            // 51.2 MB bf16 features

    const size_t need = (size_t)EMBED * K2 * 2 + (size_t)NNODES * FEAT * 2;

    wpack_kernel<<<(EMBED * K2 / 8) / 256, 256, 0, stream>>>(weight, wp);

    if (ws_size >= need) {
        fconv_kernel<<<(NNODES * FEAT / 8) / 256, 256, 0, stream>>>(features, fbf);
        gemm_fused<true><<<NBLK, 512, 0, stream>>>(features, fbf, wp, nodes, neigh, out);
    } else {
        gemm_fused<false><<<NBLK, 512, 0, stream>>>(features, fbf, wp, nodes, neigh, out);
    }
}

// Round 4
// 91.646 us; speedup vs baseline: 1.9225x; 1.0673x over previous
//
#include <hip/hip_runtime.h>

#define FEAT   256
#define K2     512      // 2*FEAT
#define NNODES 100000
#define BATCH  50000
#define NS     10
#define EMBED  256
#define BN     32
#define NBLK   ((BATCH + BN - 1) / BN)   // 1563

typedef __attribute__((ext_vector_type(8))) __bf16         bf16x8;
typedef __attribute__((ext_vector_type(8))) unsigned short ushort8;
typedef __attribute__((ext_vector_type(4))) float          f32x4;

static __device__ __forceinline__ unsigned short f2bf(float x) {
    unsigned int u = __builtin_bit_cast(unsigned int, x);
    u += 0x7FFFu + ((u >> 16) & 1u);
    return (unsigned short)(u >> 16);
}
static __device__ __forceinline__ float bf2f(unsigned short h) {
    return __builtin_bit_cast(float, (unsigned int)h << 16);
}

// ---- features f32 -> bf16 (streaming) ----
__global__ void fconv_kernel(const float* __restrict__ f,
                             unsigned short* __restrict__ fb) {
    int i = blockIdx.x * blockDim.x + threadIdx.x;
    const f32x4* src = (const f32x4*)(f + (size_t)i * 8);
    f32x4 a = src[0], b = src[1];
    ushort8 h;
    h[0]=f2bf(a[0]); h[1]=f2bf(a[1]); h[2]=f2bf(a[2]); h[3]=f2bf(a[3]);
    h[4]=f2bf(b[0]); h[5]=f2bf(b[1]); h[6]=f2bf(b[2]); h[7]=f2bf(b[3]);
    ((ushort8*)fb)[i] = h;
}

// ---- weight f32 -> bf16, fragment-major: [kt(8)][mblk(16)][ks(2)][lane(64)][8] ----
__global__ void wpack_kernel(const float* __restrict__ w,
                             unsigned short* __restrict__ wp) {
    int c    = blockIdx.x * blockDim.x + threadIdx.x;  // 16384 chunks
    int lane = c & 63;
    int ks   = (c >> 6) & 1;
    int mblk = (c >> 7) & 15;
    int kt   = c >> 11;
    int row  = mblk * 16 + (lane & 15);
    int col  = kt * 64 + ks * 32 + (lane >> 4) * 8;
    const f32x4* src = (const f32x4*)(w + row * K2 + col);
    f32x4 a = src[0], b = src[1];
    ushort8 h;
    h[0]=f2bf(a[0]); h[1]=f2bf(a[1]); h[2]=f2bf(a[2]); h[3]=f2bf(a[3]);
    h[4]=f2bf(b[0]); h[5]=f2bf(b[1]); h[6]=f2bf(b[2]); h[7]=f2bf(b[3]);
    ((ushort8*)wp)[c] = h;
}

// ---- fused: batched-MLP gather into 32KB LDS, one barrier, MFMA, relu ----
template <bool BF16F>
__global__ __launch_bounds__(512, 4) void gemm_fused(
    const float* __restrict__ features,
    const unsigned short* __restrict__ fbf,
    const unsigned short* __restrict__ wp,
    const int* __restrict__ nodes,
    const int* __restrict__ neigh,
    float* __restrict__ out) {

    __shared__ __align__(16) unsigned short lB[BN * K2];   // 32 KB

    const int tid = threadIdx.x;
    const int nb0 = blockIdx.x * BN;

    const int r  = tid >> 4;     // 0..31 batch row in tile
    const int h  = tid & 15;     // 0..15 16-col span
    const int rx = r & 7;
    const int n  = nb0 + r;
    const bool valid = n < BATCH;

    // ---- issue ALL index loads, then ALL feature loads (keep in flight) ----
    int node0 = valid ? nodes[n] : 0;
    int nidx[NS];
    #pragma unroll
    for (int s = 0; s < NS; ++s) nidx[s] = valid ? neigh[n * NS + s] : 0;

    if (BF16F) {
        const ushort8* sp = (const ushort8*)(fbf + node0 * FEAT + h * 16);
        ushort8 sa = sp[0], sb = sp[1];
        ushort8 na[NS], nb[NS];
        #pragma unroll
        for (int s = 0; s < NS; ++s) {
            const ushort8* p = (const ushort8*)(fbf + nidx[s] * FEAT + h * 16);
            na[s] = p[0];
            nb[s] = p[1];
        }
        // self half -> LDS
        {
            if (!valid) { ushort8 z = {0,0,0,0,0,0,0,0}; sa = z; sb = z; }
            const int g = h >> 2, i0 = (h & 3) * 2;
            unsigned short* dst = lB + r * K2 + g * 64;
            *(ushort8*)&dst[((i0    ) ^ rx) * 8] = sa;
            *(ushort8*)&dst[((i0 + 1) ^ rx) * 8] = sb;
        }
        // neighbor mean -> LDS
        {
            f32x4 acc[4] = {};
            #pragma unroll
            for (int s = 0; s < NS; ++s) {
                #pragma unroll
                for (int e = 0; e < 4; ++e) {
                    acc[0][e] += bf2f(na[s][e]);
                    acc[1][e] += bf2f(na[s][4 + e]);
                    acc[2][e] += bf2f(nb[s][e]);
                    acc[3][e] += bf2f(nb[s][4 + e]);
                }
            }
            ushort8 a, b;
            #pragma unroll
            for (int e = 0; e < 4; ++e) {
                a[e]     = f2bf(valid ? acc[0][e] * 0.1f : 0.f);
                a[4 + e] = f2bf(valid ? acc[1][e] * 0.1f : 0.f);
                b[e]     = f2bf(valid ? acc[2][e] * 0.1f : 0.f);
                b[4 + e] = f2bf(valid ? acc[3][e] * 0.1f : 0.f);
            }
            const int g = 4 + (h >> 2), i0 = (h & 3) * 2;
            unsigned short* dst = lB + r * K2 + g * 64;
            *(ushort8*)&dst[((i0    ) ^ rx) * 8] = a;
            *(ushort8*)&dst[((i0 + 1) ^ rx) * 8] = b;
        }
    } else {
        // f32 fallback (ws too small): modest version
        ushort8 a = {0,0,0,0,0,0,0,0}, b = a;
        if (valid) {
            const f32x4* s0 = (const f32x4*)(features + (size_t)node0 * FEAT + h * 16);
            f32x4 x0 = s0[0], x1 = s0[1], x2 = s0[2], x3 = s0[3];
            a[0]=f2bf(x0[0]); a[1]=f2bf(x0[1]); a[2]=f2bf(x0[2]); a[3]=f2bf(x0[3]);
            a[4]=f2bf(x1[0]); a[5]=f2bf(x1[1]); a[6]=f2bf(x1[2]); a[7]=f2bf(x1[3]);
            b[0]=f2bf(x2[0]); b[1]=f2bf(x2[1]); b[2]=f2bf(x2[2]); b[3]=f2bf(x2[3]);
            b[4]=f2bf(x3[0]); b[5]=f2bf(x3[1]); b[6]=f2bf(x3[2]); b[7]=f2bf(x3[3]);
        }
        {
            const int g = h >> 2, i0 = (h & 3) * 2;
            unsigned short* dst = lB + r * K2 + g * 64;
            *(ushort8*)&dst[((i0    ) ^ rx) * 8] = a;
            *(ushort8*)&dst[((i0 + 1) ^ rx) * 8] = b;
        }
        {
            float acc[16];
            #pragma unroll
            for (int e = 0; e < 16; ++e) acc[e] = 0.f;
            #pragma unroll
            for (int s = 0; s < NS; ++s) {
                const f32x4* p = (const f32x4*)(features + (size_t)nidx[s] * FEAT + h * 16);
                f32x4 x0 = p[0], x1 = p[1], x2 = p[2], x3 = p[3];
                #pragma unroll
                for (int e = 0; e < 4; ++e) {
                    acc[e]      += x0[e];
                    acc[4 + e]  += x1[e];
                    acc[8 + e]  += x2[e];
                    acc[12 + e] += x3[e];
                }
            }
            ushort8 aa, bb;
            #pragma unroll
            for (int e = 0; e < 8; ++e) {
                aa[e] = f2bf(valid ? acc[e]     * 0.1f : 0.f);
                bb[e] = f2bf(valid ? acc[8 + e] * 0.1f : 0.f);
            }
            const int g = 4 + (h >> 2), i0 = (h & 3) * 2;
            unsigned short* dst = lB + r * K2 + g * 64;
            *(ushort8*)&dst[((i0    ) ^ rx) * 8] = aa;
            *(ushort8*)&dst[((i0 + 1) ^ rx) * 8] = bb;
        }
    }
    __syncthreads();

    // ---- MFMA phase: 8 waves, wave w -> m rows [w*32, w*32+32), all 32 n-cols ----
    const int w    = tid >> 6;
    const int lane = tid & 63;
    const int lr   = lane & 15;
    const int lg   = lane >> 4;

    f32x4 acc[2][2] = {};

    #pragma unroll
    for (int kt = 0; kt < 8; ++kt) {
        bf16x8 af[2][2], bfr[2][2];
        #pragma unroll
        for (int i = 0; i < 2; ++i)
            #pragma unroll
            for (int ks = 0; ks < 2; ++ks)
                af[i][ks] = *(const bf16x8*)(wp +
                    ((((kt * 16 + w * 2 + i) * 2 + ks) * 64 + lane) << 3));
        #pragma unroll
        for (int j = 0; j < 2; ++j) {
            const int rb = j * 16 + lr;
            #pragma unroll
            for (int ks = 0; ks < 2; ++ks) {
                int ch = kt * 8 + ((ks * 4 + lg) ^ (rb & 7));
                bfr[j][ks] = *(const bf16x8*)&lB[rb * K2 + ch * 8];
            }
        }
        #pragma unroll
        for (int ks = 0; ks < 2; ++ks)
            #pragma unroll
            for (int i = 0; i < 2; ++i)
                #pragma unroll
                for (int j = 0; j < 2; ++j)
                    acc[i][j] = __builtin_amdgcn_mfma_f32_16x16x32_bf16(
                        af[i][ks], bfr[j][ks], acc[i][j], 0, 0, 0);
    }

    // ---- epilogue: relu + nontemporal store. C/D: col=lane&15, row=(lane>>4)*4+reg ----
    #pragma unroll
    for (int j = 0; j < 2; ++j) {
        const int n2 = nb0 + j * 16 + lr;
        if (n2 < BATCH) {
            #pragma unroll
            for (int i = 0; i < 2; ++i) {
                int m0 = w * 32 + i * 16 + lg * 4;
                #pragma unroll
                for (int rg = 0; rg < 4; ++rg) {
                    float v = acc[i][j][rg];
                    v = v > 0.f ? v : 0.f;
                    __builtin_nontemporal_store(v, &out[(size_t)(m0 + rg) * BATCH + n2]);
                }
            }
        }
    }
}

extern "C" void kernel_launch(void* const* d_in, const int* in_sizes, int n_in,
                              void* d_out, int out_size, void* d_ws, size_t ws_size,
                              hipStream_t stream) {
    const float* features = (const float*)d_in[0];
    const float* weight   = (const float*)d_in[1];
    const int*   nodes    = (const int*)d_in[2];
    const int*   neigh    = (const int*)d_in[3];
    float* out = (float*)d_out;

    unsigned short* wp  = (unsigned short*)d_ws;              // 256 KB packed weight
    unsigned short* fbf = wp + (size_t)EMBED * K2;            // 51.2 MB bf16 features

    const size_t need = (size_t)EMBED * K2 * 2 + (size_t)NNODES * FEAT * 2;

    wpack_kernel<<<(EMBED * K2 / 8) / 256, 256, 0, stream>>>(weight, wp);

    if (ws_size >= need) {
        fconv_kernel<<<(NNODES * FEAT / 8) / 256, 256, 0, stream>>>(features, fbf);
        gemm_fused<true><<<NBLK, 512, 0, stream>>>(features, fbf, wp, nodes, neigh, out);
    } else {
        gemm_fused<false><<<NBLK, 512, 0, stream>>>(features, fbf, wp, nodes, neigh, out);
    }
}